// Round 3
// baseline (852.712 us; speedup 1.0000x reference)
//
#include <hip/hip_runtime.h>
#include <math.h>

typedef _Float16 half8 __attribute__((ext_vector_type(8)));
typedef float floatx4 __attribute__((ext_vector_type(4)));

constexpr int CCH = 480, TT = 4, FY = 45, FX = 80;
constexpr int SN = 32, NROI = 512;
constexpr int KDIM = CCH * 49;      // 23520
constexpr int NDF_ = 1024, NC = 50;
constexpr float SCALE_X = 80.0f / 1280.0f;
constexpr float SCALE_Y = 45.0f / 720.0f;

constexpr int BM = 128, BN = 128, BK = 32;
constexpr int SK = 15;
constexpr int ITERS = (KDIM / BK) / SK;   // 49
static_assert(SK * ITERS * BK == KDIM, "split-K must tile K exactly");

constexpr int CG = 8;               // channels per ROI block
constexpr int FSTR = 3604;          // padded frame stride (floats): %32==20, 16B-aligned

// ---------------------------------------------------------------------------
// W fp32 -> exact fp16 hi/lo split (x = hi + lo/2048), once per call.
// ---------------------------------------------------------------------------
__global__ __launch_bounds__(256) void wconv_kernel(
    const float* __restrict__ W, _Float16* __restrict__ Whi, _Float16* __restrict__ Wlo)
{
    const size_t n = blockIdx.x;
    const float* src = W + n * KDIM;
    _Float16* dh = Whi + n * KDIM;
    _Float16* dl = Wlo + n * KDIM;
    for (int kc = threadIdx.x * 8; kc < KDIM; kc += 256 * 8) {
        float4 a = *(const float4*)(src + kc);
        float4 b = *(const float4*)(src + kc + 4);
        float xs[8] = {a.x, a.y, a.z, a.w, b.x, b.y, b.z, b.w};
        _Float16 hs[8], ls[8];
        #pragma unroll
        for (int e = 0; e < 8; ++e) {
            _Float16 h = (_Float16)xs[e];
            hs[e] = h;
            ls[e] = (_Float16)((xs[e] - (float)h) * 2048.0f);
        }
        *(half8*)(dh + kc) = *(half8*)hs;
        *(half8*)(dl + kc) = *(half8*)ls;
    }
}

// ---------------------------------------------------------------------------
// ROI-align via LDS-staged frames. Block = (batch, 8-channel group).
// Coalesced float4 frame load -> LDS; thread = (roi r, channel lane cl).
// Output fp16 hi/lo, layout [r][c*49+pos] (matches W K-order).
// ---------------------------------------------------------------------------
__global__ __launch_bounds__(256) void roi_lds_kernel(
    const float* __restrict__ zvis,     // [16,480,4,45,80]
    const float* __restrict__ bboxs,    // [16,32,4]
    _Float16* __restrict__ phi,
    _Float16* __restrict__ plo)
{
    const int b  = blockIdx.x;          // 0..15
    const int cg = blockIdx.y;          // 0..59
    const int tid = threadIdx.x;
    const int c0 = cg * CG;

    __shared__ float sF[CG * FSTR];     // ~115.3 KB

    // Phase 1: stage 8 channels of the t=3 slice, coalesced.
    for (int i = tid; i < CG * 900; i += 256) {
        int ch  = i / 900;
        int off = (i - ch * 900) * 4;
        float4 v = *(const float4*)(zvis + (((size_t)(b * CCH + c0 + ch)) * TT + 3) * 3600 + off);
        *(float4*)(sF + ch * FSTR + off) = v;
    }
    __syncthreads();

    // Phase 2: one (roi, channel) pair per thread.
    const int r  = tid >> 3;            // 0..31
    const int cl = tid & 7;
    const int roi = b * SN + r;

    const float x1 = bboxs[roi * 4 + 0] * SCALE_X - 0.5f;
    const float y1 = bboxs[roi * 4 + 1] * SCALE_Y - 0.5f;
    const float x2 = bboxs[roi * 4 + 2] * SCALE_X - 0.5f;
    const float y2 = bboxs[roi * 4 + 3] * SCALE_Y - 0.5f;
    const float bw = (x2 - x1) / 7.0f;
    const float bh = (y2 - y1) / 7.0f;

    int   xo_l[7], xo_h[7];
    float lxv[7], vxv[7];
    int   yo_l[7], yo_h[7];
    float lyv[7], vyv[7];
    #pragma unroll
    for (int i = 0; i < 7; ++i) {
        float x = x1 + ((float)i + 0.5f) * bw;
        vxv[i] = (x > -1.0f && x < (float)FX) ? 1.0f : 0.0f;
        float xc = fminf(fmaxf(x, 0.0f), (float)(FX - 1));
        int xl = (int)floorf(xc);
        xo_l[i] = xl;
        xo_h[i] = min(xl + 1, FX - 1);
        lxv[i] = xc - (float)xl;

        float y = y1 + ((float)i + 0.5f) * bh;
        vyv[i] = (y > -1.0f && y < (float)FY) ? 1.0f : 0.0f;
        float yc = fminf(fmaxf(y, 0.0f), (float)(FY - 1));
        int yl = (int)floorf(yc);
        yo_l[i] = yl * FX;
        yo_h[i] = min(yl + 1, FY - 1) * FX;
        lyv[i] = yc - (float)yl;
    }

    const float* f = sF + cl * FSTR;
    _Float16* oh = phi + (size_t)roi * KDIM + (c0 + cl) * 49;
    _Float16* ol = plo + (size_t)roi * KDIM + (c0 + cl) * 49;

    #pragma unroll
    for (int py = 0; py < 7; ++py) {
        const float ly = lyv[py], hy = 1.0f - lyv[py], vy = vyv[py];
        const int rl = yo_l[py], rh = yo_h[py];
        #pragma unroll
        for (int px = 0; px < 7; ++px) {
            const float lx = lxv[px], hx = 1.0f - lxv[px];
            const float v = vy * vxv[px];
            float val = f[rl + xo_l[px]] * (hy * hx)
                      + f[rl + xo_h[px]] * (hy * lx)
                      + f[rh + xo_l[px]] * (ly * hx)
                      + f[rh + xo_h[px]] * (ly * lx);
            val *= v;
            _Float16 hi = (_Float16)val;
            _Float16 lo = (_Float16)((val - (float)hi) * 2048.0f);
            oh[py * 7 + px] = hi;
            ol[py * 7 + px] = lo;
        }
    }
}

// ---------------------------------------------------------------------------
// Z bias init: Z[m][n] = b_vis[n] + norms[m]*w_spc[n] + b_spc[n]
// ---------------------------------------------------------------------------
__global__ __launch_bounds__(256) void bias_init_kernel(
    const float* __restrict__ b_vis, const float* __restrict__ norms,
    const float* __restrict__ w_spc, const float* __restrict__ b_spc,
    float* __restrict__ Z)
{
    const int m = blockIdx.x;
    const int n = threadIdx.x * 4;
    const float nm = norms[m];
    float4 bv = *(const float4*)(b_vis + n);
    float4 ws = *(const float4*)(w_spc + n);
    float4 bs = *(const float4*)(b_spc + n);
    float4 o;
    o.x = bv.x + nm * ws.x + bs.x;
    o.y = bv.y + nm * ws.y + bs.y;
    o.z = bv.z + nm * ws.z + bs.z;
    o.w = bv.w + nm * ws.w + bs.w;
    *(float4*)(Z + (size_t)m * NDF_ + n) = o;
}

// ---------------------------------------------------------------------------
// Split-K MFMA GEMM, 3-term fp16 compensation. All operands pre-split fp16;
// A and B both staged via async global_load_lds width-16.
// ---------------------------------------------------------------------------
__device__ __forceinline__ void async_cp16(const void* g, void* l) {
    __builtin_amdgcn_global_load_lds(
        (const __attribute__((address_space(1))) void*)g,
        (__attribute__((address_space(3))) void*)l, 16, 0, 0);
}

__global__ __launch_bounds__(256, 2) void gemm3_kernel(
    const _Float16* __restrict__ Ahi, const _Float16* __restrict__ Alo,
    const _Float16* __restrict__ Bhi, const _Float16* __restrict__ Blo,
    float* __restrict__ Z)
{
    __shared__ __align__(16) _Float16 sAh[BM * BK];
    __shared__ __align__(16) _Float16 sAl[BM * BK];
    __shared__ __align__(16) _Float16 sBh[BN * BK];
    __shared__ __align__(16) _Float16 sBl[BN * BK];

    const int tid  = threadIdx.x;
    const int wave = tid >> 6;
    const int lane = tid & 63;
    const int n0 = blockIdx.x * BN;
    const int m0 = blockIdx.y * BM;
    const int kz = blockIdx.z;

    floatx4 ach[4][4], acm[4][4];
    #pragma unroll
    for (int i = 0; i < 4; ++i)
        #pragma unroll
        for (int j = 0; j < 4; ++j) {
            ach[i][j] = (floatx4){0.f, 0.f, 0.f, 0.f};
            acm[i][j] = (floatx4){0.f, 0.f, 0.f, 0.f};
        }

    // staging map: chunk = 16 rows x 32 halfs (1 KB); lane -> row l>>2, col (l&3)*8
    const int chunk = wave * 2;
    const int row0  = chunk * 16 + (lane >> 2);
    const int colh  = (lane & 3) * 8;

    const int wr = (wave >> 1) * 64;
    const int wc = (wave & 1) * 64;
    const int frow = lane & 15;
    const int ko   = (lane >> 4) * 8;

    for (int it = 0; it < ITERS; ++it) {
        const int k0 = (kz * ITERS + it) * BK;

        #pragma unroll
        for (int i = 0; i < 2; ++i) {
            const size_t goA = (size_t)(m0 + row0 + i * 16) * KDIM + k0 + colh;
            const size_t goB = (size_t)(n0 + row0 + i * 16) * KDIM + k0 + colh;
            async_cp16(Ahi + goA, (void*)(sAh + (chunk + i) * 512));
            async_cp16(Alo + goA, (void*)(sAl + (chunk + i) * 512));
            async_cp16(Bhi + goB, (void*)(sBh + (chunk + i) * 512));
            async_cp16(Blo + goB, (void*)(sBl + (chunk + i) * 512));
        }

        __syncthreads();

        half8 bh[4], bl[4];
        #pragma unroll
        for (int ni = 0; ni < 4; ++ni) {
            const int n_l = wc + ni * 16 + frow;
            bh[ni] = *(const half8*)(sBh + n_l * 32 + ko);
            bl[ni] = *(const half8*)(sBl + n_l * 32 + ko);
        }
        #pragma unroll
        for (int mi = 0; mi < 4; ++mi) {
            const int m_l = wr + mi * 16 + frow;
            half8 ah = *(const half8*)(sAh + m_l * 32 + ko);
            half8 al = *(const half8*)(sAl + m_l * 32 + ko);
            #pragma unroll
            for (int ni = 0; ni < 4; ++ni) {
                ach[mi][ni] = __builtin_amdgcn_mfma_f32_16x16x32_f16(ah, bh[ni], ach[mi][ni], 0, 0, 0);
                acm[mi][ni] = __builtin_amdgcn_mfma_f32_16x16x32_f16(ah, bl[ni], acm[mi][ni], 0, 0, 0);
                acm[mi][ni] = __builtin_amdgcn_mfma_f32_16x16x32_f16(al, bh[ni], acm[mi][ni], 0, 0, 0);
            }
        }
        __syncthreads();
    }

    const float inv2048 = 1.0f / 2048.0f;
    #pragma unroll
    for (int mi = 0; mi < 4; ++mi)
        #pragma unroll
        for (int ni = 0; ni < 4; ++ni)
            #pragma unroll
            for (int rr = 0; rr < 4; ++rr) {
                int gm = m0 + wr + mi * 16 + (lane >> 4) * 4 + rr;
                int gn = n0 + wc + ni * 16 + (lane & 15);
                unsafeAtomicAdd(&Z[(size_t)gm * NDF_ + gn],
                                ach[mi][ni][rr] + acm[mi][ni][rr] * inv2048);
            }
}

// ---------------------------------------------------------------------------
// Clustering: dist to 50 centroids, s=(1+dist)^-1 normalized, argmax
// ---------------------------------------------------------------------------
__global__ __launch_bounds__(256) void cluster_kernel(
    const float* __restrict__ Z, const float* __restrict__ cent,
    float* __restrict__ S, float* __restrict__ Cc)
{
    const int r = blockIdx.x;
    const int tid = threadIdx.x;
    __shared__ float sz[NDF_];
    __shared__ float sd[NC];

    for (int d = tid; d < NDF_; d += 256) sz[d] = Z[(size_t)r * NDF_ + d];
    __syncthreads();

    const int wave = tid >> 6;
    const int lane = tid & 63;
    for (int k = wave; k < NC; k += 4) {
        float sum = 0.0f;
        const float* ck = cent + (size_t)k * NDF_;
        for (int d = lane; d < NDF_; d += 64) {
            float df = sz[d] - ck[d];
            sum += df * df;
        }
        #pragma unroll
        for (int off = 32; off > 0; off >>= 1) sum += __shfl_down(sum, off, 64);
        if (lane == 0) sd[k] = 1.0f / (1.0f + sqrtf(sum));
    }
    __syncthreads();

    if (tid == 0) {
        float tot = 0.0f;
        for (int k = 0; k < NC; k++) tot += sd[k];
        float inv = 1.0f / tot;
        float best = -1.0f;
        int bi = 0;
        for (int k = 0; k < NC; k++) {
            float sv = sd[k] * inv;
            S[(size_t)r * NC + k] = sv;
            if (sv > best) { best = sv; bi = k; }
        }
        Cc[r] = (float)bi;
    }
}

// ---------------------------------------------------------------------------
extern "C" void kernel_launch(void* const* d_in, const int* in_sizes, int n_in,
                              void* d_out, int out_size, void* d_ws, size_t ws_size,
                              hipStream_t stream)
{
    const float* z_vis     = (const float*)d_in[0];
    const float* bboxs     = (const float*)d_in[1];
    const float* norms     = (const float*)d_in[2];
    const float* w_vis     = (const float*)d_in[3];
    const float* b_vis     = (const float*)d_in[4];
    const float* w_spc     = (const float*)d_in[5];
    const float* b_spc     = (const float*)d_in[6];
    const float* centroids = (const float*)d_in[7];

    _Float16* phi = (_Float16*)d_ws;                      // 24.1 MB
    _Float16* plo = phi + (size_t)NROI * KDIM;            // 24.1 MB
    _Float16* whi = plo + (size_t)NROI * KDIM;            // 48.2 MB
    _Float16* wlo = whi + (size_t)NDF_ * KDIM;            // 48.2 MB  (total ~144.6 MB)

    float* z_out = (float*)d_out;                         // [512,1024]
    float* s_out = z_out + (size_t)NROI * NDF_;           // [512,50]
    float* c_out = s_out + (size_t)NROI * NC;             // [512]

    wconv_kernel<<<NDF_, 256, 0, stream>>>(w_vis, whi, wlo);

    dim3 rgrid(16, CCH / CG);
    roi_lds_kernel<<<rgrid, 256, 0, stream>>>(z_vis, bboxs, phi, plo);

    bias_init_kernel<<<NROI, 256, 0, stream>>>(b_vis, norms, w_spc, b_spc, z_out);

    dim3 ggrid(NDF_ / BN, NROI / BM, SK);
    gemm3_kernel<<<ggrid, 256, 0, stream>>>(phi, plo, whi, wlo, z_out);

    cluster_kernel<<<NROI, 256, 0, stream>>>(z_out, centroids, s_out, c_out);
}